// Round 3
// baseline (142.487 us; speedup 1.0000x reference)
//
#include <hip/hip_runtime.h>
#include <cmath>

#define P 5
#define LBV 0.0f
#define UBV 0.5f
#define RFV 1.03f
#define ALPHA 0.1f
#define OMEGA 0.05f
#define BETA 0.05f
#define MU 0.01f
#define NTHR 256

#define AS1 __attribute__((address_space(1)))
#define AS3 __attribute__((address_space(3)))

// tanh via HW v_exp_f32 + v_rcp_f32. For |x| large, exp(-2|x|)->0 => r->1.
__device__ __forceinline__ float fast_tanh(float x) {
    float ax = fabsf(x);
    float t  = __expf(-2.0f * ax);
    float r  = (1.0f - t) * __builtin_amdgcn_rcpf(1.0f + t);
    return copysignf(r, x);
}

// One thread per sample. Only layer k=3 contributes to the output (reference
// loop re-consumes the ORIGINAL x1/x2; only the last iteration survives).
// Memory plan: x2 staged via global_load_lds (wave-uniform base + lane*16,
// the only legal pattern); eps/x1 direct (small L1-resident spans); cov
// stored direct per-thread (L2 merges the 100B/lane spans into full lines).
__global__ __launch_bounds__(NTHR, 5) void portfolio_kernel(
    const float* __restrict__ x1,
    const float* __restrict__ x2,
    const float* __restrict__ eps,
    const float* __restrict__ W,
    float* __restrict__ out, int B)
{
    __shared__ float sX2[NTHR * P * P];      // 25.6 KB, linear copy of block's x2

    const int tid  = threadIdx.x;
    const int b0   = blockIdx.x * NTHR;
    const int lane = tid & 63;
    const int wv   = tid >> 6;               // wave id, uniform per wave

    // Direct per-thread loads, issued early so they fly with the DMA.
    float x1v = x1[b0 + tid];
    const float* ge = eps + (size_t)3 * B * P + (size_t)(b0 + tid) * P;
    float e[P];
    #pragma unroll
    for (int j = 0; j < P; ++j) e[j] = ge[j];

    // Async global->LDS staging of this block's 6400-float x2 chunk.
    // Each instr: 64 lanes x 16B = 1KB; 24 full chunks + 1 remainder.
    const float* gx2 = x2 + (size_t)b0 * (P * P);
    #pragma unroll
    for (int i = 0; i < 6; ++i) {
        int c = (i * 4 + wv) * 256;          // float offset of this wave's 1KB chunk
        __builtin_amdgcn_global_load_lds((const AS1 void*)(gx2 + c + lane * 4),
                                         (AS3 void*)(&sX2[c]), 16, 0, 0);
    }
    if (wv == 0) {                           // floats 6144..6399
        __builtin_amdgcn_global_load_lds((const AS1 void*)(gx2 + 6144 + lane * 4),
                                         (AS3 void*)(&sX2[6144]), 16, 0, 0);
    }
    __syncthreads();                         // drains vmcnt -> LDS valid

    // This sample's x2 row (lane stride 25 words -> 2-way bank alias, free).
    float r2[P * P];
    #pragma unroll
    for (int i = 0; i < P * P; ++i) r2[i] = sX2[tid * (P * P) + i];

    // Ce[i] = sum_j x2[i][j] * eps[j]
    float Ce[P];
    #pragma unroll
    for (int i = 0; i < P; ++i) {
        float s = 0.0f;
        #pragma unroll
        for (int j = 0; j < P; ++j) s = fmaf(r2[i * P + j], e[j], s);
        Ce[i] = s;
    }

    float R[P], h[P];
    #pragma unroll
    for (int i = 0; i < P; ++i) { R[i] = MU + Ce[i]; h[i] = R[i]; }

    // 3 bias-free Linear(5,5) + tanh. W[3] access is wave-uniform -> s_loads.
    const float* Wl = W + 3 * 3 * P * P;
    #pragma unroll
    for (int l = 0; l < 3; ++l) {
        float hn[P];
        #pragma unroll
        for (int i = 0; i < P; ++i) {
            float s = 0.0f;
            #pragma unroll
            for (int j = 0; j < P; ++j) s = fmaf(h[j], Wl[l * P * P + i * P + j], s);
            hn[i] = fast_tanh(s);
        }
        #pragma unroll
        for (int i = 0; i < P; ++i) h[i] = hn[i];
    }

    // softmax over P — h in (-1,1) so no max-subtraction needed
    float w[P], ssum = 0.0f;
    #pragma unroll
    for (int i = 0; i < P; ++i) { w[i] = __expf(h[i]); ssum += w[i]; }
    float rs = __builtin_amdgcn_rcpf(ssum);
    #pragma unroll
    for (int i = 0; i < P; ++i) w[i] *= rs;

    // water-filling rebalance; break==freeze (matches reference done semantics)
    float oldv[P], nw[P];
    #pragma unroll
    for (int i = 0; i < P; ++i) {
        oldv[i] = w[i];
        nw[i]   = fminf(fmaxf(w[i], LBV), UBV);
    }
    #pragma unroll
    for (int it = 0; it < 8; ++it) {
        float leftover = 0.0f;
        #pragma unroll
        for (int i = 0; i < P; ++i) leftover += oldv[i] - nw[i];
        float mk[P], msum = 0.0f;
        #pragma unroll
        for (int i = 0; i < P; ++i) {
            mk[i] = (nw[i] != UBV) ? nw[i] : 0.0f;
            msum += mk[i];
        }
        float scale = leftover * __builtin_amdgcn_rcpf(msum);
        float n2[P];
        #pragma unroll
        for (int i = 0; i < P; ++i) n2[i] = fmaf(scale, mk[i], nw[i]);
        bool cont = false;
        #pragma unroll
        for (int i = 0; i < P; ++i) cont = cont || (n2[i] > UBV);
        #pragma unroll
        for (int i = 0; i < P; ++i) {
            oldv[i] = n2[i];
            nw[i]   = cont ? fminf(fmaxf(n2[i], LBV), UBV) : n2[i];
        }
        if (!cont) break;
    }

    // wealth = x1 * RF * sum_i nw[i] * (1 + R[i])
    float ws = 0.0f;
    #pragma unroll
    for (int i = 0; i < P; ++i) ws = fmaf(nw[i], 1.0f + R[i], ws);
    out[b0 + tid] = x1v * ws * RFV;

    // curr_cov[i][j] = OMEGA + ALPHA*x2[i][j] + BETA*Ce[j]^2, stored direct.
    // Wave covers a contiguous 6.4KB span; L2 write-back merges to full lines.
    float ce2[P];
    #pragma unroll
    for (int j = 0; j < P; ++j) ce2[j] = Ce[j] * Ce[j];
    float* gout = out + B + (size_t)(b0 + tid) * (P * P);
    #pragma unroll
    for (int i = 0; i < P; ++i) {
        #pragma unroll
        for (int j = 0; j < P; ++j)
            gout[i * P + j] = fmaf(BETA, ce2[j], fmaf(ALPHA, r2[i * P + j], OMEGA));
    }
}

extern "C" void kernel_launch(void* const* d_in, const int* in_sizes, int n_in,
                              void* d_out, int out_size, void* d_ws, size_t ws_size,
                              hipStream_t stream) {
    const float* x1  = (const float*)d_in[0];
    const float* x2  = (const float*)d_in[1];
    const float* eps = (const float*)d_in[2];
    const float* W   = (const float*)d_in[3];
    float* out = (float*)d_out;
    const int B = in_sizes[0];           // 524288
    const int blocks = B / NTHR;
    portfolio_kernel<<<blocks, NTHR, 0, stream>>>(x1, x2, eps, W, out, B);
}

// Round 4
// 134.847 us; speedup vs baseline: 1.0567x; 1.0567x over previous
//
#include <hip/hip_runtime.h>
#include <cmath>

#define P 5
#define LBV 0.0f
#define UBV 0.5f
#define RFV 1.03f
#define ALPHA 0.1f
#define OMEGA 0.05f
#define BETA 0.05f
#define MU 0.01f
#define NTHR 256

#define AS1 __attribute__((address_space(1)))
#define AS3 __attribute__((address_space(3)))

// tanh via HW v_exp_f32 + v_rcp_f32. For |x| large, exp(-2|x|)->0 => r->1.
__device__ __forceinline__ float fast_tanh(float x) {
    float ax = fabsf(x);
    float t  = __expf(-2.0f * ax);
    float r  = (1.0f - t) * __builtin_amdgcn_rcpf(1.0f + t);
    return copysignf(r, x);
}

// One thread per sample. Only layer k=3 contributes to the output (reference
// loop re-consumes the ORIGINAL x1/x2; only the last iteration survives).
//
// Memory plan (request-rate aware — R3 lesson: scatter stores cost ~64 L2
// sector-requests per instruction, ~21us of TA time):
//   in : x2 + eps staged via global_load_lds DMA (1KB/instr, contiguous)
//   out: cov written to own LDS row (stride-25 -> 2 lanes/bank, free), then
//        linear dwordx4 coalesced store-out (16 sectors/wave/instr).
__global__ __launch_bounds__(NTHR, 5) void portfolio_kernel(
    const float* __restrict__ x1,
    const float* __restrict__ x2,
    const float* __restrict__ eps,
    const float* __restrict__ W,
    float* __restrict__ out, int B)
{
    __shared__ alignas(16) float sX2[NTHR * P * P];  // 25.6 KB, linear x2 copy
    __shared__ alignas(16) float sE[NTHR * P];       // 5 KB, linear eps copy

    const int tid  = threadIdx.x;
    const int b0   = blockIdx.x * NTHR;
    const int lane = tid & 63;
    const int wv   = tid >> 6;               // wave id, uniform per wave

    float x1v = x1[b0 + tid];                // coalesced direct load

    // x2: 6400 floats = 25 chunks of 1KB. Waves 0..3 take 6 each; wave 0 +1.
    const float* gx2 = x2 + (size_t)b0 * (P * P);
    #pragma unroll
    for (int i = 0; i < 6; ++i) {
        int c = (i * 4 + wv) * 256;
        __builtin_amdgcn_global_load_lds((const AS1 void*)(gx2 + c + lane * 4),
                                         (AS3 void*)(&sX2[c]), 16, 0, 0);
    }
    if (wv == 0)
        __builtin_amdgcn_global_load_lds((const AS1 void*)(gx2 + 6144 + lane * 4),
                                         (AS3 void*)(&sX2[6144]), 16, 0, 0);

    // eps[3] slice: 1280 floats = 5 chunks. Waves 0..3 take 1; wave 0 +1.
    const float* ge = eps + (size_t)3 * B * P + (size_t)b0 * P;
    __builtin_amdgcn_global_load_lds((const AS1 void*)(ge + wv * 256 + lane * 4),
                                     (AS3 void*)(&sE[wv * 256]), 16, 0, 0);
    if (wv == 0)
        __builtin_amdgcn_global_load_lds((const AS1 void*)(ge + 1024 + lane * 4),
                                         (AS3 void*)(&sE[1024]), 16, 0, 0);

    __syncthreads();                         // drains vmcnt -> LDS valid

    // Own x2 row into registers (lane stride 25 words -> 2-way alias, free).
    float r2[P * P];
    #pragma unroll
    for (int i = 0; i < P * P; ++i) r2[i] = sX2[tid * (P * P) + i];

    float e[P];
    #pragma unroll
    for (int j = 0; j < P; ++j) e[j] = sE[tid * P + j];

    // Ce[i] = sum_j x2[i][j] * eps[j]
    float Ce[P];
    #pragma unroll
    for (int i = 0; i < P; ++i) {
        float s = 0.0f;
        #pragma unroll
        for (int j = 0; j < P; ++j) s = fmaf(r2[i * P + j], e[j], s);
        Ce[i] = s;
    }

    float R[P], h[P];
    #pragma unroll
    for (int i = 0; i < P; ++i) { R[i] = MU + Ce[i]; h[i] = R[i]; }

    // 3 bias-free Linear(5,5) + tanh. W[3] access wave-uniform -> s_loads.
    const float* Wl = W + 3 * 3 * P * P;
    #pragma unroll
    for (int l = 0; l < 3; ++l) {
        float hn[P];
        #pragma unroll
        for (int i = 0; i < P; ++i) {
            float s = 0.0f;
            #pragma unroll
            for (int j = 0; j < P; ++j) s = fmaf(h[j], Wl[l * P * P + i * P + j], s);
            hn[i] = fast_tanh(s);
        }
        #pragma unroll
        for (int i = 0; i < P; ++i) h[i] = hn[i];
    }

    // softmax over P — h in (-1,1) so no max-subtraction needed
    float w[P], ssum = 0.0f;
    #pragma unroll
    for (int i = 0; i < P; ++i) { w[i] = __expf(h[i]); ssum += w[i]; }
    float rs = __builtin_amdgcn_rcpf(ssum);
    #pragma unroll
    for (int i = 0; i < P; ++i) w[i] *= rs;

    // water-filling rebalance; break==freeze (matches reference semantics)
    float oldv[P], nw[P];
    #pragma unroll
    for (int i = 0; i < P; ++i) {
        oldv[i] = w[i];
        nw[i]   = fminf(fmaxf(w[i], LBV), UBV);
    }
    #pragma unroll
    for (int it = 0; it < 8; ++it) {
        float leftover = 0.0f;
        #pragma unroll
        for (int i = 0; i < P; ++i) leftover += oldv[i] - nw[i];
        float mk[P], msum = 0.0f;
        #pragma unroll
        for (int i = 0; i < P; ++i) {
            mk[i] = (nw[i] != UBV) ? nw[i] : 0.0f;
            msum += mk[i];
        }
        float scale = leftover * __builtin_amdgcn_rcpf(msum);
        float n2[P];
        #pragma unroll
        for (int i = 0; i < P; ++i) n2[i] = fmaf(scale, mk[i], nw[i]);
        bool cont = false;
        #pragma unroll
        for (int i = 0; i < P; ++i) cont = cont || (n2[i] > UBV);
        #pragma unroll
        for (int i = 0; i < P; ++i) {
            oldv[i] = n2[i];
            nw[i]   = cont ? fminf(fmaxf(n2[i], LBV), UBV) : n2[i];
        }
        if (!cont) break;
    }

    // wealth = x1 * RF * sum_i nw[i] * (1 + R[i])  (coalesced store)
    float ws = 0.0f;
    #pragma unroll
    for (int i = 0; i < P; ++i) ws = fmaf(nw[i], 1.0f + R[i], ws);
    out[b0 + tid] = x1v * ws * RFV;

    // cov into own LDS row (only this thread touches it -> no barrier needed)
    float ce2[P];
    #pragma unroll
    for (int j = 0; j < P; ++j) ce2[j] = Ce[j] * Ce[j];
    #pragma unroll
    for (int i = 0; i < P; ++i) {
        #pragma unroll
        for (int j = 0; j < P; ++j)
            sX2[tid * (P * P) + i * P + j] =
                fmaf(BETA, ce2[j], fmaf(ALPHA, r2[i * P + j], OMEGA));
    }

    __syncthreads();

    // coalesced dwordx4 store-out: 1600 float4 = 6*256 + 64
    const float4* sOut = (const float4*)sX2;
    float4* gcov = (float4*)(out + B + (size_t)blockIdx.x * (NTHR * P * P));
    #pragma unroll
    for (int r = 0; r < 6; ++r)
        gcov[r * NTHR + tid] = sOut[r * NTHR + tid];
    if (tid < 64)
        gcov[6 * NTHR + tid] = sOut[6 * NTHR + tid];
}

extern "C" void kernel_launch(void* const* d_in, const int* in_sizes, int n_in,
                              void* d_out, int out_size, void* d_ws, size_t ws_size,
                              hipStream_t stream) {
    const float* x1  = (const float*)d_in[0];
    const float* x2  = (const float*)d_in[1];
    const float* eps = (const float*)d_in[2];
    const float* W   = (const float*)d_in[3];
    float* out = (float*)d_out;
    const int B = in_sizes[0];           // 524288
    const int blocks = B / NTHR;
    portfolio_kernel<<<blocks, NTHR, 0, stream>>>(x1, x2, eps, W, out, B);
}